// Round 9
// baseline (111.615 us; speedup 1.0000x reference)
//
#include <hip/hip_runtime.h>

#define BB    8
#define CC    256
#define HWN   16384       // 128*128
#define PP    30
#define PPAD  32          // padded proto count (2 dummy rows)
#define KD    128
#define GG    5
// d_out float offsets
#define OFF_Q   (33554432u)             // 8*256*128*128
#define OFF_SIM (OFF_Q + 30720u)        // + 30*8*128

typedef float f32x2 __attribute__((ext_vector_type(2)));

// ---- kernel 1: fused q-projection + padded A/c0 build (256 blocks) ---------
// A[b,p,c] (p<30) = sum_k q[p,b,k]*Wk[k,c];  A rows 30,31 = 0
// c0[b,p]  (p<30) = sum_k q[p,b,k]*bk[k];    c0 rows 30,31 = -1e30
__global__ __launch_bounds__(256) void proj_kernel(
    const float* __restrict__ proto,  // [P,B,C]
    const float* __restrict__ Wq,     // [6,128,C]
    const float* __restrict__ bq,     // [6,128]
    const float* __restrict__ Wk,     // [128,C]
    const float* __restrict__ bk,     // [128]
    float* __restrict__ qout,         // [P,B,128] (into d_out)
    float* __restrict__ A,            // [B,PPAD,C] (ws)
    float* __restrict__ c0)           // [B,PPAD]   (ws)
{
    const int pb = blockIdx.x;        // p*B + b   (p in [0,32))
    const int p = pb / BB, b = pb % BB;
    const int tid = threadIdx.x;

    if (p >= PP) {                    // pad rows
        A[((size_t)b * PPAD + p) * CC + tid] = 0.f;
        if (tid == 0) c0[b * PPAD + p] = -1e30f;
        return;
    }
    const int g = p / GG;

    __shared__ float ps[CC];
    __shared__ float qs[KD];

    for (int c = tid; c < CC; c += 256) ps[c] = proto[(size_t)(p * BB + b) * CC + c];
    __syncthreads();

    if (tid < KD) {
        const float* wrow = Wq + (size_t)(g * KD + tid) * CC;
        float a = 0.f;
        #pragma unroll 4
        for (int c = 0; c < CC; ++c) a += ps[c] * wrow[c];
        a += bq[g * KD + tid];
        qout[(size_t)(p * BB + b) * KD + tid] = a;
        qs[tid] = a;
    }
    __syncthreads();

    float a = 0.f;
    #pragma unroll 4
    for (int k = 0; k < KD; ++k) a += qs[k] * Wk[k * CC + tid];
    A[((size_t)b * PPAD + p) * CC + tid] = a;

    if (tid == 0) {
        float s = 0.f;
        for (int k = 0; k < KD; ++k) s += qs[k] * bk[k];
        c0[b * PPAD + p] = s;
    }
}

// ---- kernel 2: fused sim + softmax-max + weighted output -------------------
// 2 positions/thread. Block = 128 positions x 4 waves; wave q owns protos
// [q*8, q*8+8) over ALL 256 channels (low reg pressure, no AGPR traffic).
// A broadcast via v_readlane: lane l holds A[b][p][chi*64+l], chi static.
__global__ __launch_bounds__(256, 4) void fused_kernel(
    const float* __restrict__ X,    // [B,C,HW]
    const float* __restrict__ A,    // [B,PPAD,C]
    const float* __restrict__ c0,   // [B,PPAD]
    float* __restrict__ out0,       // [B,C,HW]
    float* __restrict__ sim)        // [B,PP,HW]
{
    const int b    = blockIdx.y;
    const int tid  = threadIdx.x;
    const int lane = tid & 63;
    const int q    = tid >> 6;
    const int p0   = q * 8;
    const int n0   = blockIdx.x * 128 + lane * 2;

    __shared__ float c0s[PPAD];
    __shared__ float redmax[4][64][2];
    __shared__ float redsum[4][64][2];

    if (tid < PPAD) c0s[tid] = c0[b * PPAD + tid];

    // lane l holds A[b][p0+pl][chi*64 + l]
    float a[8][4];
    #pragma unroll
    for (int pl = 0; pl < 8; ++pl)
        #pragma unroll
        for (int chi = 0; chi < 4; ++chi)
            a[pl][chi] = A[((size_t)(b * PPAD + p0 + pl)) * CC + chi * 64 + lane];

    __syncthreads();                  // c0s ready (hides a[] load latency)

    float acc0[8], acc1[8];
    #pragma unroll
    for (int pl = 0; pl < 8; ++pl) { acc0[pl] = 0.f; acc1[pl] = 0.f; }

    const float* xb = X + (size_t)b * CC * HWN + n0;

    #pragma unroll
    for (int chi = 0; chi < 4; ++chi) {
        #pragma unroll 4
        for (int cl = 0; cl < 64; ++cl) {     // cl uniform -> SGPR lane select
            const f32x2 xv = *(const f32x2*)(xb + (size_t)(chi * 64 + cl) * HWN);
            #pragma unroll
            for (int pl = 0; pl < 8; ++pl) {
                const float av = __int_as_float(
                    __builtin_amdgcn_readlane(__float_as_int(a[pl][chi]), cl));
                acc0[pl] += av * xv.x;
                acc1[pl] += av * xv.y;
            }
        }
    }

    // add c0, store sim (wave-uniform p), partial max
    float pm0 = -1e30f, pm1 = -1e30f;
    #pragma unroll
    for (int pl = 0; pl < 8; ++pl) {
        const int p = p0 + pl;
        const float cv = c0s[p];
        acc0[pl] += cv;
        acc1[pl] += cv;
        if (p < PP) {
            f32x2 sv;
            sv.x = acc0[pl];
            sv.y = acc1[pl];
            __builtin_nontemporal_store(sv,
                (f32x2*)(sim + ((size_t)b * PP + p) * HWN + n0));
        }
        pm0 = fmaxf(pm0, acc0[pl]);
        pm1 = fmaxf(pm1, acc1[pl]);
    }
    redmax[q][lane][0] = pm0;
    redmax[q][lane][1] = pm1;
    __syncthreads();

    const float m0 = fmaxf(fmaxf(redmax[0][lane][0], redmax[1][lane][0]),
                           fmaxf(redmax[2][lane][0], redmax[3][lane][0]));
    const float m1 = fmaxf(fmaxf(redmax[0][lane][1], redmax[1][lane][1]),
                           fmaxf(redmax[2][lane][1], redmax[3][lane][1]));
    float ps0 = 0.f, ps1 = 0.f;
    #pragma unroll
    for (int pl = 0; pl < 8; ++pl) {          // pads: exp(-huge) = 0
        ps0 += __expf((acc0[pl] - m0) * (1.f / 6.f));
        ps1 += __expf((acc1[pl] - m1) * (1.f / 6.f));
    }
    redsum[q][lane][0] = ps0;
    redsum[q][lane][1] = ps1;
    __syncthreads();

    f32x2 wv;                                  // all waves compute redundantly
    wv.x = 1.f / (redsum[0][lane][0] + redsum[1][lane][0] +
                  redsum[2][lane][0] + redsum[3][lane][0]);
    wv.y = 1.f / (redsum[0][lane][1] + redsum[1][lane][1] +
                  redsum[2][lane][1] + redsum[3][lane][1]);

    // weighted output: wave q writes channel quarter q (X re-read is L2-hot)
    float* ob = out0 + (size_t)b * CC * HWN + n0;
    #pragma unroll 8
    for (int i = 0; i < 64; ++i) {
        const size_t off = (size_t)(q * 64 + i) * HWN;
        f32x2 x = __builtin_nontemporal_load((const f32x2*)(xb + off));
        f32x2 o = x * wv;
        __builtin_nontemporal_store(o, (f32x2*)(ob + off));
    }
}

extern "C" void kernel_launch(void* const* d_in, const int* in_sizes, int n_in,
                              void* d_out, int out_size, void* d_ws, size_t ws_size,
                              hipStream_t stream) {
    const float* X     = (const float*)d_in[0];
    const float* proto = (const float*)d_in[1];
    const float* Wk    = (const float*)d_in[2];
    const float* bk    = (const float*)d_in[3];
    const float* Wq    = (const float*)d_in[4];
    const float* bq    = (const float*)d_in[5];

    float* out  = (float*)d_out;
    float* qout = out + OFF_Q;
    float* sim  = out + OFF_SIM;

    float* A  = (float*)d_ws;              // 8*32*256 = 65536 floats
    float* c0 = A + BB * PPAD * CC;        // 256 floats

    proj_kernel<<<PPAD * BB, 256, 0, stream>>>(proto, Wq, bq, Wk, bk, qout, A, c0);

    dim3 grid(HWN / 128, BB);              // 128 x 8 = 1024 blocks
    fused_kernel<<<grid, 256, 0, stream>>>(X, A, c0, out, sim);
}

// Round 10
// 88.484 us; speedup vs baseline: 1.2614x; 1.2614x over previous
//
#include <hip/hip_runtime.h>

#define BB    8
#define CC    256
#define HWN   16384       // 128*128
#define PP    30
#define PPAD  32          // padded proto count (2 zero rows)
#define KD    128
#define GG    5
// d_out float offsets
#define OFF_Q   (33554432u)             // 8*256*128*128
#define OFF_SIM (OFF_Q + 30720u)        // + 30*8*128

typedef float  f32x2  __attribute__((ext_vector_type(2)));
typedef float  f32x16 __attribute__((ext_vector_type(16)));
typedef short  short8 __attribute__((ext_vector_type(8)));

static __device__ __forceinline__ short f2bf(float f) {   // f32 -> bf16 RNE
    unsigned u = __float_as_uint(f);
    u += 0x7fffu + ((u >> 16) & 1u);
    return (short)(u >> 16);
}

// ---- kernel 1: q-projection + A in bf16 MFMA-fragment order + c0 -----------
// A[b,p,c] = sum_k q[p,b,k]*Wk[k,c]  (rows 30,31 zero)
// Fragment layout for v_mfma_f32_32x32x16_bf16 A-operand:
//   lane = p + 32*((c%16)/8), elem j = c%8, block kb = c/16
//   Afrag[((b*16+kb)*64 + lane)*8 + j]
__global__ __launch_bounds__(256) void proj_kernel(
    const float* __restrict__ proto,  // [P,B,C]
    const float* __restrict__ Wq,     // [6,128,C]
    const float* __restrict__ bq,     // [6,128]
    const float* __restrict__ Wk,     // [128,C]
    const float* __restrict__ bk,     // [128]
    float* __restrict__ qout,         // [P,B,128] (into d_out)
    short* __restrict__ Afrag,        // [B,16,64,8] bf16 (ws)
    float* __restrict__ c0)           // [B,PPAD]   (ws)
{
    const int pb = blockIdx.x;        // p*B + b  (p in [0,32))
    const int p = pb / BB, b = pb % BB;
    const int tid = threadIdx.x;      // = channel c

    const int kb = tid >> 4, hi = (tid >> 3) & 1, j = tid & 7;
    const size_t fidx = ((size_t)(b * 16 + kb) * 64 + p + 32 * hi) * 8 + j;

    if (p >= PP) {                    // pad rows
        Afrag[fidx] = 0;
        if (tid == 0) c0[b * PPAD + p] = -1e30f;
        return;
    }
    const int g = p / GG;

    __shared__ float ps[CC];
    __shared__ float qs[KD];

    for (int c = tid; c < CC; c += 256)
        ps[c] = proto[(size_t)(p * BB + b) * CC + c];
    __syncthreads();

    if (tid < KD) {
        const float* wrow = Wq + (size_t)(g * KD + tid) * CC;
        float a = 0.f;
        #pragma unroll 4
        for (int c = 0; c < CC; ++c) a += ps[c] * wrow[c];
        a += bq[g * KD + tid];
        qout[(size_t)(p * BB + b) * KD + tid] = a;
        qs[tid] = a;
    }
    __syncthreads();

    float a = 0.f;
    #pragma unroll 4
    for (int k = 0; k < KD; ++k) a += qs[k] * Wk[k * CC + tid];
    Afrag[fidx] = f2bf(a);

    if (tid == 0) {
        float s = 0.f;
        for (int k = 0; k < KD; ++k) s += qs[k] * bk[k];
        c0[b * PPAD + p] = s;
    }
}

// ---- kernel 2: MFMA sim + softmax-max + weighted output --------------------
// Block = 4 waves x 32 positions = 128 positions. Wave w computes the full
// 32-proto x 32-pos sim tile via 16x mfma_f32_32x32x16_bf16 (K=256), then
// softmax over protos in-register (C/D layout: col=lane&31,
// row=(reg&3)+8*(reg>>2)+4*(lane>>5)), then block-wide weighted-output pass.
__global__ __launch_bounds__(256) void fused_kernel(
    const float* __restrict__ X,     // [B,C,HW]
    const short* __restrict__ Afrag, // [B,16,64,8] bf16
    const float* __restrict__ c0,    // [B,PPAD]
    float* __restrict__ out0,        // [B,C,HW]
    float* __restrict__ sim)         // [B,PP,HW]
{
    const int b    = blockIdx.y;
    const int tid  = threadIdx.x;
    const int lane = tid & 63;
    const int wid  = tid >> 6;
    const int col  = lane & 31;
    const int half = lane >> 5;
    const int n0   = blockIdx.x * 128;
    const int nw   = n0 + wid * 32;       // wave's 32 positions

    __shared__ float c0s[PPAD];
    __shared__ float wbuf[128];
    __shared__ float redm[4][2][32];
    __shared__ float reds[4][2][32];

    if (tid < PPAD) c0s[tid] = c0[b * PPAD + tid];

    // preload this lane's 16 A-fragments (16B each, L2-broadcast)
    const short8* af8 = (const short8*)Afrag;
    short8 af[16];
    #pragma unroll
    for (int kb = 0; kb < 16; ++kb)
        af[kb] = af8[(size_t)(b * 16 + kb) * 64 + lane];

    f32x16 acc = {};
    const float* xcol = X + (size_t)b * CC * HWN + nw + col;

    #pragma unroll
    for (int kb = 0; kb < 16; ++kb) {
        float xf[8];
        #pragma unroll
        for (int j = 0; j < 8; ++j)       // B-frag: k = half*8+j, n = col
            xf[j] = xcol[(size_t)(kb * 16 + half * 8 + j) * HWN];
        short8 bfr;
        #pragma unroll
        for (int j = 0; j < 8; ++j) bfr[j] = f2bf(xf[j]);
        acc = __builtin_amdgcn_mfma_f32_32x32x16_bf16(af[kb], bfr, acc, 0, 0, 0);
    }
    __syncthreads();                      // c0s ready

    // add c0, store sim, in-lane max over 16 rows
    float v[16];
    float pm = -1e30f;
    #pragma unroll
    for (int r = 0; r < 16; ++r) {
        const int row = (r & 3) + 8 * (r >> 2) + 4 * half;
        const float t = acc[r] + c0s[row];
        v[r] = t;
        pm = fmaxf(pm, t);
        if (row < PP)
            sim[((size_t)b * PP + row) * HWN + nw + col] = t;
    }
    redm[wid][half][col] = pm;
    __syncthreads();
    const float m = fmaxf(pm, redm[wid][1 - half][col]);

    float s = 0.f;
    #pragma unroll
    for (int r = 0; r < 16; ++r)          // pads: exp(-huge) = 0
        s += __expf((v[r] - m) * (1.f / 6.f));
    reds[wid][half][col] = s;
    __syncthreads();
    const float w = 1.f / (s + reds[wid][1 - half][col]);
    if (half == 0) wbuf[wid * 32 + col] = w;
    __syncthreads();

    // weighted output: 2 pos/thread, wave wid owns channel quarter wid
    f32x2 wv2;
    wv2.x = wbuf[lane * 2];
    wv2.y = wbuf[lane * 2 + 1];
    const int n0p = n0 + lane * 2;
    const float* xb = X    + (size_t)b * CC * HWN + n0p;
    float*       ob = out0 + (size_t)b * CC * HWN + n0p;
    #pragma unroll 8
    for (int i = 0; i < 64; ++i) {
        const size_t off = (size_t)(wid * 64 + i) * HWN;
        f32x2 x = __builtin_nontemporal_load((const f32x2*)(xb + off));
        f32x2 o = x * wv2;
        __builtin_nontemporal_store(o, (f32x2*)(ob + off));
    }
}

extern "C" void kernel_launch(void* const* d_in, const int* in_sizes, int n_in,
                              void* d_out, int out_size, void* d_ws, size_t ws_size,
                              hipStream_t stream) {
    const float* X     = (const float*)d_in[0];
    const float* proto = (const float*)d_in[1];
    const float* Wk    = (const float*)d_in[2];
    const float* bk    = (const float*)d_in[3];
    const float* Wq    = (const float*)d_in[4];
    const float* bq    = (const float*)d_in[5];

    float* out  = (float*)d_out;
    float* qout = out + OFF_Q;
    float* sim  = out + OFF_SIM;

    short* Afrag = (short*)d_ws;                  // 8*16*64*8 = 65536 shorts
    float* c0    = (float*)(Afrag + BB * 16 * 64 * 8);  // 256 floats

    proj_kernel<<<PPAD * BB, 256, 0, stream>>>(proto, Wq, bq, Wk, bk, qout, Afrag, c0);

    dim3 grid(HWN / 128, BB);                     // 128 x 8 = 1024 blocks
    fused_kernel<<<grid, 256, 0, stream>>>(X, Afrag, c0, out, sim);
}